// Round 9
// baseline (420.627 us; speedup 1.0000x reference)
//
#include <hip/hip_runtime.h>
#include <stdint.h>

typedef __bf16 bf16x8 __attribute__((ext_vector_type(8)));
typedef float f32x4 __attribute__((ext_vector_type(4)));
typedef unsigned short u16x8 __attribute__((ext_vector_type(8)));
typedef unsigned int u32x4 __attribute__((ext_vector_type(4)));

__device__ __forceinline__ unsigned short f2bf(float f) {
    unsigned int u = __builtin_bit_cast(unsigned int, f);
    unsigned int r = u + 0x7fffu + ((u >> 16) & 1u);
    return (unsigned short)(r >> 16);
}

// v_cvt_pk_bf16_f32: lo <- bf16(a), hi <- bf16(b)
__device__ __forceinline__ unsigned int cvt_pk_bf16(float a, float b) {
    unsigned int r;
    asm("v_cvt_pk_bf16_f32 %0, %1, %2" : "=v"(r) : "v"(a), "v"(b));
    return r;
}

// async global->LDS, 16B per lane. LDS dest = wave-uniform base + lane*16.
__device__ __forceinline__ void async16(const void* g, void* l) {
    __builtin_amdgcn_global_load_lds(
        (const __attribute__((address_space(1))) void*)g,
        (__attribute__((address_space(3))) void*)l, 16, 0, 0);
}

// ---------------------------------------------------------------------------
// Bodies for the fused prep kernels (block-granular branching).
// ---------------------------------------------------------------------------

// x fp32 -> bf16, 8 elems/thread at flat index i
__device__ __forceinline__ void cast_body(
    const float* __restrict__ src, unsigned short* __restrict__ dst, int i)
{
    const float* f = src + (size_t)i * 8;
    f32x4 a = *reinterpret_cast<const f32x4*>(f);
    f32x4 b = *reinterpret_cast<const f32x4*>(f + 4);
    u16x8 r;
    r[0]=f2bf(a[0]); r[1]=f2bf(a[1]); r[2]=f2bf(a[2]); r[3]=f2bf(a[3]);
    r[4]=f2bf(b[0]); r[5]=f2bf(b[1]); r[6]=f2bf(b[2]); r[7]=f2bf(b[3]);
    *reinterpret_cast<u16x8*>(dst + (size_t)i * 8) = r;
}

// W fp32 [R][Cc] -> bf16 W^T [Cc][R], one 64x64 tile at (bx,by), XOR-swizzled LDS
__device__ __forceinline__ void tcast_body(
    const float* __restrict__ src, unsigned short* __restrict__ dst,
    int R, int Cc, int bx, int by, int tid, unsigned short* St)
{
    const int r0 = by * 64, c0 = bx * 64;
    const int lr  = tid >> 2;          // 0..63
    const int lcb = (tid & 3) * 16;    // 0,16,32,48
    const float* sp = src + (size_t)(r0 + lr) * Cc + c0 + lcb;
    #pragma unroll
    for (int u = 0; u < 4; u++) {
        f32x4 v = *reinterpret_cast<const f32x4*>(sp + 4 * u);
        #pragma unroll
        for (int e = 0; e < 4; e++) {
            int c = lcb + 4 * u + e;
            St[c * 64 + (((lr >> 3) ^ ((c >> 4) & 3)) << 3) + (lr & 7)] = f2bf(v[e]);
        }
    }
    __syncthreads();
    #pragma unroll
    for (int i = 0; i < 2; i++) {
        int ck = tid + 256 * i;
        int c = ck >> 3, ch = ck & 7;
        u16x8 val = *reinterpret_cast<const u16x8*>(&St[c * 64 + ((ch ^ ((c >> 4) & 3)) << 3)]);
        *reinterpret_cast<u16x8*>(dst + (size_t)(c0 + c) * R + r0 + ch * 8) = val;
    }
}

// V-part of qkv -> VT [b][h][d][t'] with per-32 t-permutation matching the
// swapped-QK^T P layout (see flash_attn). One 64x64 tile at (tx, dy, bh).
__device__ __forceinline__ void vtrans_body(
    const unsigned short* __restrict__ qkv, unsigned short* __restrict__ VT,
    int tx, int dy, int bh, int tid, unsigned short* St)
{
    const int T = 2048, CH = 6144;
    const int b = bh >> 4, h = bh & 15;
    const int t0 = tx * 64, d0 = dy * 64;
    const int lr  = tid >> 2;
    const int lcb = (tid & 3) * 16;
    const unsigned short* sp = qkv + (size_t)(b * T + t0 + lr) * CH + 4096 + h * 128 + d0 + lcb;
    u16x8 v0 = *reinterpret_cast<const u16x8*>(sp);
    u16x8 v1 = *reinterpret_cast<const u16x8*>(sp + 8);
    #pragma unroll
    for (int e = 0; e < 8; e++) {
        int c = lcb + e;
        St[c * 64 + (((lr >> 3) ^ ((c >> 4) & 3)) << 3) + (lr & 7)] = v0[e];
        c = lcb + 8 + e;
        St[c * 64 + (((lr >> 3) ^ ((c >> 4) & 3)) << 3) + (lr & 7)] = v1[e];
    }
    __syncthreads();
    #pragma unroll
    for (int i = 0; i < 2; i++) {
        int ck = tid + 256 * i;
        int d = ck >> 3, ch = ck & 7;
        const int Q = ch & 3, B32 = ch >> 2;
        u16x8 val;
        #pragma unroll
        for (int e = 0; e < 4; e++) {
            int ta = 32 * B32 + 4 * Q + e;        // first half of chunk
            int tb = ta + 16;                     // second half
            val[e]     = St[d * 64 + (((ta >> 3) ^ ((d >> 4) & 3)) << 3) + (ta & 7)];
            val[4 + e] = St[d * 64 + (((tb >> 3) ^ ((d >> 4) & 3)) << 3) + (tb & 7)];
        }
        *reinterpret_cast<u16x8*>(VT + (size_t)(bh * 128 + d0 + d) * T + t0 + ch * 8) = val;
    }
}

// ---------------------------------------------------------------------------
// prep1 = cast_bf16(x) UNION transpose_cast(Wqkv).
// ---------------------------------------------------------------------------
__global__ __launch_bounds__(256) void prep1(
    const float* __restrict__ x, unsigned short* __restrict__ xb,
    const float* __restrict__ Wqkv, unsigned short* __restrict__ WqkvT)
{
    __shared__ unsigned short St[64 * 64];
    const int bid = blockIdx.x, tid = threadIdx.x;
    if (bid < 4096) {
        cast_body(x, xb, bid * 256 + tid);
    } else {
        const int b2 = bid - 4096;
        tcast_body(Wqkv, WqkvT, 2048, 6144, b2 % 96, b2 / 96, tid, St);
    }
}

// ---------------------------------------------------------------------------
// prep2 = vtrans(qkv) UNION transpose_cast(Wout).
// ---------------------------------------------------------------------------
__global__ __launch_bounds__(256) void prep2(
    const unsigned short* __restrict__ qkv, unsigned short* __restrict__ VT,
    const float* __restrict__ Wout, unsigned short* __restrict__ WoutT)
{
    __shared__ unsigned short St[64 * 64];
    const int bid = blockIdx.x, tid = threadIdx.x;
    if (bid < 2048) {
        vtrans_body(qkv, VT, bid % 32, (bid >> 5) & 1, bid >> 6, tid, St);
    } else {
        const int b2 = bid - 2048;
        tcast_body(Wout, WoutT, 2048, 2048, b2 % 32, b2 / 32, tid, St);
    }
}

// ---------------------------------------------------------------------------
// 128x128 double-buffered GEMM, single-barrier counted pipeline + T2 swizzle
// (PROVEN 133us/775TF). Used for GEMM2 (and GEMM1 fallback).
// ---------------------------------------------------------------------------
__global__ __launch_bounds__(256) void gemm_bt(
    const unsigned short* __restrict__ A,   // [M][K] bf16
    const unsigned short* __restrict__ BT,  // [N][K] bf16
    void* __restrict__ C, int M, int N, int K, int cF32)
{
    __shared__ unsigned short As[2][128 * 32];
    __shared__ unsigned short Bs[2][128 * 32];
    const int tid = threadIdx.x;
    const int w = tid >> 6, lane = tid & 63;
    const int quad = lane >> 4, l16 = lane & 15;
    const int wm = (w >> 1) * 64, wn = (w & 1) * 64;
    const int m0 = blockIdx.y * 128, n0 = blockIdx.x * 128;

    const int srow = w * 16 + (lane >> 2);
    const int scol = ((lane & 3) ^ ((lane >> 3) & 3)) * 8;   // inverse-swizzled source chunk
    const unsigned short* aG = A  + (size_t)(m0 + srow) * K + scol;
    const unsigned short* bG = BT + (size_t)(n0 + srow) * K + scol;
    const int ldsO = (w * 16) * 32;            // wave-uniform LDS offset

    const int kch = (quad ^ ((l16 >> 1) & 3)) * 8;   // swizzled fragment chunk

    f32x4 acc[4][4] = {};
    const int nkt = K >> 5;

    async16(aG, &As[0][ldsO]);
    async16(aG + (size_t)64 * K, &As[0][ldsO + 64 * 32]);
    async16(bG, &Bs[0][ldsO]);
    async16(bG + (size_t)64 * K, &Bs[0][ldsO + 64 * 32]);
    asm volatile("s_waitcnt vmcnt(0)\n\ts_barrier" ::: "memory");

    int ct = 0;
    for (int t = 0; t < nkt; ++t) {
        if (t + 1 < nkt) {
            const int k1 = (t + 1) * 32;
            async16(aG + k1, &As[ct ^ 1][ldsO]);
            async16(aG + (size_t)64 * K + k1, &As[ct ^ 1][ldsO + 64 * 32]);
            async16(bG + k1, &Bs[ct ^ 1][ldsO]);
            async16(bG + (size_t)64 * K + k1, &Bs[ct ^ 1][ldsO + 64 * 32]);
        }

        bf16x8 af[4], bf[4];
        #pragma unroll
        for (int i = 0; i < 4; i++)
            af[i] = *reinterpret_cast<const bf16x8*>(&As[ct][(wm + i * 16 + l16) * 32 + kch]);
        #pragma unroll
        for (int c = 0; c < 4; c++)
            bf[c] = *reinterpret_cast<const bf16x8*>(&Bs[ct][(wn + c * 16 + l16) * 32 + kch]);

        __builtin_amdgcn_s_setprio(1);
        #pragma unroll
        for (int i = 0; i < 4; i++)
            #pragma unroll
            for (int c = 0; c < 4; c++)
                acc[i][c] = __builtin_amdgcn_mfma_f32_16x16x32_bf16(af[i], bf[c], acc[i][c], 0, 0, 0);
        __builtin_amdgcn_s_setprio(0);

        asm volatile("s_waitcnt vmcnt(0) lgkmcnt(0)\n\ts_barrier" ::: "memory");
        ct ^= 1;
    }

    #pragma unroll
    for (int i = 0; i < 4; i++)
        #pragma unroll
        for (int c = 0; c < 4; c++)
            #pragma unroll
            for (int r = 0; r < 4; r++) {
                const int row = m0 + wm + i * 16 + quad * 4 + r;
                const int col = n0 + wn + c * 16 + l16;
                const size_t off = (size_t)row * N + col;
                if (cF32) ((float*)C)[off] = acc[i][c][r];
                else ((unsigned short*)C)[off] = f2bf(acc[i][c][r]);
            }
}

// ---------------------------------------------------------------------------
// 256x256 GEMM, 3-buffer LDS RING (96 KiB dynamic), BK=32, distance-2
// prefetch with counted vmcnt(4) (never 0 in steady state), 2 phases/tile
// with barrier-pair + setprio MFMA clusters (T3+T4+T5+T2).
//   8 waves (2M x 4N), wave tile 128x64, acc[8][4].
//   Per-wave loads: 4/tile (ph1: A halves, ph2: B halves).
//   Accounting: prologue stages t0,t1 (8) -> vmcnt(4) = t0 landed.
//     tile t stages t+2 (4 loads); end-of-tile outstanding = 8 -> vmcnt(4)
//     retires exactly t+1's loads (issued 2 tiles ~2000cyc earlier).
//   Swizzle identical to gemm_bt (key (l16>>1)&3; inverse on global source;
//   compute mapping byte-identical to r6's gemm256 which PASSED correctness).
// ---------------------------------------------------------------------------
__global__ __launch_bounds__(512) void gemm256r(
    const unsigned short* __restrict__ A,   // [M][K] bf16
    const unsigned short* __restrict__ BT,  // [N][K] bf16
    unsigned short* __restrict__ Cb,        // [M][N] bf16
    int M, int N, int K)
{
    extern __shared__ unsigned short lds[];   // A: 3x8192 elems @0, B: 3x8192 @24576
    const int tid = threadIdx.x;
    const int w = tid >> 6, lane = tid & 63;
    const int quad = lane >> 4, l16 = lane & 15;
    const int wm = w >> 2, wn = w & 3;                 // 2 x 4 wave grid
    const int m0 = blockIdx.y * 256, n0 = blockIdx.x * 256;
    const int nkt = K >> 5;

    // staging: per load instr, 512 threads cover 128 rows x 4 chunks (16B).
    // row = tid>>2, chunk = tid&3; source chunk inverse-swizzled with key
    // (row>>1)&3 = (lane>>3)&3 (wave row-base w*16 and +128 contribute 0).
    const int sRow = w * 16 + (lane >> 2);
    const int sCol = ((lane & 3) ^ ((lane >> 3) & 3)) * 8;
    const unsigned short* aG = A  + (size_t)(m0 + sRow) * K + sCol;
    const unsigned short* bG = BT + (size_t)(n0 + sRow) * K + sCol;
    const int ldsW = w * 512;                          // wave slice within a 128-row half

    // fragment reads: swizzled chunk, key uniform (row offsets all mult of 16)
    const int kch = (quad ^ ((l16 >> 1) & 3)) * 8;
    const int aRow0 = wm * 128 + l16;
    const int bRow0 = wn * 64 + l16;

    f32x4 acc[8][4] = {};

    unsigned short* const Ab0 = lds;
    unsigned short* const Bb0 = lds + 24576;

    // prologue: stage tiles 0 and 1 (A+B each)
    {
        #pragma unroll
        for (int t0 = 0; t0 < 2; t0++) {
            const int k0 = t0 * 32;
            async16(aG + k0, Ab0 + t0 * 8192 + ldsW);
            async16(aG + (size_t)128 * K + k0, Ab0 + t0 * 8192 + 4096 + ldsW);
            async16(bG + k0, Bb0 + t0 * 8192 + ldsW);
            async16(bG + (size_t)128 * K + k0, Bb0 + t0 * 8192 + 4096 + ldsW);
        }
    }
    asm volatile("s_waitcnt vmcnt(4)\n\ts_barrier" ::: "memory");

    int rb = 0, rs = 2;                                // ring: current, stage=(rb+2)%3
    for (int t = 0; t < nkt; ++t) {
        const unsigned short* Ac = Ab0 + rb * 8192;
        const unsigned short* Bc = Bb0 + rb * 8192;
        const bool doStage = (t + 2 < nkt);
        const int k2 = (t + 2) * 32;

        // ---- phase 1: stage A(t+2); read af[0..3], bf[0..3]; 16 MFMA ----
        if (doStage) {
            async16(aG + k2, Ab0 + rs * 8192 + ldsW);
            async16(aG + (size_t)128 * K + k2, Ab0 + rs * 8192 + 4096 + ldsW);
        }
        bf16x8 af[4], bf[4];
        #pragma unroll
        for (int i = 0; i < 4; i++)
            af[i] = *reinterpret_cast<const bf16x8*>(Ac + (aRow0 + i * 16) * 32 + kch);
        #pragma unroll
        for (int c = 0; c < 4; c++)
            bf[c] = *reinterpret_cast<const bf16x8*>(Bc + (bRow0 + c * 16) * 32 + kch);
        asm volatile("s_barrier" ::: "memory");
        asm volatile("s_waitcnt lgkmcnt(0)" ::: "memory");
        __builtin_amdgcn_s_setprio(1);
        #pragma unroll
        for (int i = 0; i < 4; i++)
            #pragma unroll
            for (int c = 0; c < 4; c++)
                acc[i][c] = __builtin_amdgcn_mfma_f32_16x16x32_bf16(af[i], bf[c], acc[i][c], 0, 0, 0);
        __builtin_amdgcn_s_setprio(0);
        asm volatile("s_barrier" ::: "memory");

        // ---- phase 2: stage B(t+2); read af[4..7]; 16 MFMA ----
        if (doStage) {
            async16(bG + k2, Bb0 + rs * 8192 + ldsW);
            async16(bG + (size_t)128 * K + k2, Bb0 + rs * 8192 + 4096 + ldsW);
        }
        bf16x8 ag[4];
        #pragma unroll
        for (int i = 0; i < 4; i++)
            ag[i] = *reinterpret_cast<const bf16x8*>(Ac + (aRow0 + (i + 4) * 16) * 32 + kch);
        asm volatile("s_barrier" ::: "memory");
        asm volatile("s_waitcnt lgkmcnt(0)" ::: "memory");
        __builtin_amdgcn_s_setprio(1);
        #pragma unroll
        for (int i = 0; i < 4; i++)
            #pragma unroll
            for (int c = 0; c < 4; c++)
                acc[i + 4][c] = __builtin_amdgcn_mfma_f32_16x16x32_bf16(ag[i], bf[c], acc[i + 4][c], 0, 0, 0);
        __builtin_amdgcn_s_setprio(0);

        // ---- tile end: counted wait (retires exactly t+1's loads) ----
        if (doStage)
            asm volatile("s_waitcnt vmcnt(4)\n\ts_barrier" ::: "memory");
        else
            asm volatile("s_waitcnt vmcnt(0)\n\ts_barrier" ::: "memory");

        rb = (rb == 2) ? 0 : rb + 1;
        rs = (rs == 2) ? 0 : rs + 1;
    }

    #pragma unroll
    for (int i = 0; i < 8; i++)
        #pragma unroll
        for (int c = 0; c < 4; c++)
            #pragma unroll
            for (int r = 0; r < 4; r++) {
                const int row = m0 + wm * 128 + i * 16 + quad * 4 + r;
                const int col = n0 + wn * 64 + c * 16 + l16;
                Cb[(size_t)row * N + col] = f2bf(acc[i][c][r]);
            }
}

// ---------------------------------------------------------------------------
// Flash attention v2 (causal), swapped-QK^T / lane-local softmax,
// double-buffered K/V staging with counted-vmcnt pipeline (round-2 version).
// ---------------------------------------------------------------------------
__global__ __launch_bounds__(256, 2) void flash_attn(
    const unsigned short* __restrict__ qkv,
    const unsigned short* __restrict__ VT,
    unsigned short* __restrict__ Out)
{
    const int T = 2048, CH = 6144;
    __shared__ unsigned short KsBuf[2][64 * 128];   // [kv][d-chunk swizzled]
    __shared__ unsigned short VtBuf[2][128 * 64];   // [d][kv'-chunk swizzled]

    const int tid = threadIdx.x;
    const int w = tid >> 6, lane = tid & 63;
    const int quad = lane >> 4, l16 = lane & 15;
    const int bh = blockIdx.y, b = bh >> 4, h = bh & 15;
    const int q0 = (gridDim.x - 1 - blockIdx.x) * 128;   // heavy blocks first

    const float sc = 0.08838834764831845f * 1.4426950408889634f;
    const float NINF = -__builtin_inff();

    // Q fragments (B-operand), scale folded in
    bf16x8 qf[2][4];
    #pragma unroll
    for (int st = 0; st < 2; st++) {
        const unsigned short* qrow = qkv + (size_t)(b * T + q0 + w * 32 + st * 16 + l16) * CH + h * 128;
        #pragma unroll
        for (int dc = 0; dc < 4; dc++) {
            u16x8 raw = *reinterpret_cast<const u16x8*>(qrow + dc * 32 + quad * 8);
            u16x8 scl;
            #pragma unroll
            for (int e = 0; e < 8; e++) {
                float f = __builtin_bit_cast(float, (unsigned int)raw[e] << 16);
                scl[e] = f2bf(f * sc);
            }
            qf[st][dc] = __builtin_bit_cast(bf16x8, scl);
        }
    }

    f32x4 o[2][8] = {};
    float m_i[2] = {NINF, NINF};
    float l_i[2] = {0.f, 0.f};
    const int xsw = l16 & 7;

    const int kRow = (lane >> 4);
    const int kCh  = lane & 15;
    const int vRow = (lane >> 3);
    const int vCh  = lane & 7;

    auto stageKV = [&](int kv0, unsigned short* kp, unsigned short* vp) {
        #pragma unroll
        for (int i = 0; i < 4; i++) {
            const int r0 = i * 16 + w * 4;
            const int kv = r0 + kRow;
            const int ch = kCh ^ (kv & 7);
            async16(qkv + (size_t)(b * T + kv0 + kv) * CH + 2048 + h * 128 + ch * 8,
                    kp + r0 * 128);
        }
        #pragma unroll
        for (int i = 0; i < 4; i++) {
            const int r0 = i * 32 + w * 8;
            const int d = r0 + vRow;
            const int ch = vCh ^ (d & 7);
            async16(VT + ((size_t)bh * 128 + d) * T + kv0 + ch * 8,
                    vp + r0 * 64);
        }
    };

    unsigned short* kc = KsBuf[0];
    unsigned short* vc = VtBuf[0];
    unsigned short* kn = KsBuf[1];
    unsigned short* vn = VtBuf[1];

    const int nt = (q0 + 128) / 64;

    stageKV(0, kc, vc);
    asm volatile("s_waitcnt vmcnt(0)\n\ts_barrier" ::: "memory");

    for (int t = 0; t < nt; ++t) {
        const int kv0 = t * 64;
        if (t + 1 < nt) stageKV((t + 1) * 64, kn, vn);

        // ---- S^T = K Q^T ----
        f32x4 s[2][4] = {};
        __builtin_amdgcn_s_setprio(1);
        #pragma unroll
        for (int dc = 0; dc < 4; dc++)
            #pragma unroll
            for (int ntt = 0; ntt < 4; ntt++) {
                bf16x8 kf = *reinterpret_cast<const bf16x8*>(
                    &kc[(ntt * 16 + l16) * 128 + (((dc * 4 + quad) ^ xsw) << 3)]);
                s[0][ntt] = __builtin_amdgcn_mfma_f32_16x16x32_bf16(kf, qf[0][dc], s[0][ntt], 0, 0, 0);
                s[1][ntt] = __builtin_amdgcn_mfma_f32_16x16x32_bf16(kf, qf[1][dc], s[1][ntt], 0, 0, 0);
            }
        __builtin_amdgcn_s_setprio(0);

        // ---- softmax, lane-local rows ----
        unsigned int pk[2][4][2];
        #pragma unroll
        for (int st = 0; st < 2; st++) {
            const int qs = q0 + w * 32 + st * 16;
            const int qrow = qs + l16;
            if (kv0 + 63 > qs) {                     // diagonal: causal mask
                #pragma unroll
                for (int ntt = 0; ntt < 4; ntt++)
                    #pragma unroll
                    for (int r = 0; r < 4; r++)
                        if (kv0 + ntt * 16 + quad * 4 + r > qrow) s[st][ntt][r] = NINF;
            }
            float mx = fmaxf(fmaxf(fmaxf(s[st][0][0], s[st][0][1]), fmaxf(s[st][0][2], s[st][0][3])),
                             fmaxf(fmaxf(s[st][1][0], s[st][1][1]), fmaxf(s[st][1][2], s[st][1][3])));
            mx = fmaxf(mx,
                 fmaxf(fmaxf(fmaxf(s[st][2][0], s[st][2][1]), fmaxf(s[st][2][2], s[st][2][3])),
                       fmaxf(fmaxf(s[st][3][0], s[st][3][1]), fmaxf(s[st][3][2], s[st][3][3]))));
            mx = fmaxf(mx, __shfl_xor(mx, 16));
            mx = fmaxf(mx, __shfl_xor(mx, 32));

            const float mold = m_i[st];
            if (!__all(mx <= mold + 8.0f)) {         // rescale (rare)
                const float mnew = fmaxf(mold, mx);
                const float alpha = exp2f(mold - mnew);
                m_i[st] = mnew;
                l_i[st] *= alpha;
                #pragma unroll
                for (int r = 0; r < 4; r++) {
                    const float a = __shfl(alpha, quad * 4 + r);
                    #pragma unroll
                    for (int c = 0; c < 8; c++) o[st][c][r] *= a;
                }
            }
            const float m = m_i[st];
            float p[4][4];
            #pragma unroll
            for (int ntt = 0; ntt < 4; ntt++)
                #pragma unroll
                for (int r = 0; r < 4; r++)
                    p[ntt][r] = exp2f(s[st][ntt][r] - m);
            float ps = ((p[0][0] + p[0][1]) + (p[0][2] + p[0][3]))
                     + ((p[1][0] + p[1][1]) + (p[1][2] + p[1][3]))
                     + ((p[2][0] + p[2][1]) + (p[2][2] + p[2][3]))
                     + ((p[3][0] + p[3][1]) + (p[3][2] + p[3][3]));
            ps += __shfl_xor(ps, 16);
            ps += __shfl_xor(ps, 32);
            l_i[st] += ps;
            #pragma unroll
            for (int ntt = 0; ntt < 4; ntt++) {
                pk[st][ntt][0] = cvt_pk_bf16(p[ntt][0], p[ntt][1]);
                pk[st][ntt][1] = cvt_pk_bf16(p[ntt][2], p[ntt][3]);
            }
        }

        // ---- O += P V ----
        __builtin_amdgcn_s_setprio(1);
        #pragma unroll
        for (int kc2 = 0; kc2 < 2; kc2++) {
            u32x4 a0, a1;
            a0[0] = pk[0][2*kc2][0];   a0[1] = pk[0][2*kc2][1];
            a0[2] = pk[0][2*kc2+1][0]; a0[3] = pk[0][2*kc2+1][1];
            a1[0] = pk[1][2*kc2][0];   a1[1] = pk[1][2*kc2][1];
            a1[2] = pk[1][2*kc2+1][0]; a1[3] = pk[1][2*kc2+1][1];
            const bf16x8 pf0 = __builtin_bit_cast(bf16x8, a0);
            const bf16x8 pf1 = __builtin_bit_cast(bf16x8, a1);
            #pragma unroll
            for (int c = 0; c < 8; c++) {
                bf16x8 vf = *reinterpret_cast<const bf16x8*>(
                    &vc[(c * 16 + l16) * 64 + (((kc2 * 4 + quad) ^ xsw) << 3)]);
                o[0][c] = __builtin_amdgcn_mfma_f32_16x16x32_bf16(pf0, vf, o[0][c], 0, 0, 0);
                o[1][c] = __builtin_amdgcn_mfma_f32_16x16x32_bf16(pf1, vf, o[1][c], 0, 0, 0);
            }
        }
        __builtin_amdgcn_s_setprio(0);

        asm volatile("s_waitcnt vmcnt(0) lgkmcnt(0)\n\ts_barrier" ::: "memory");

        unsigned short* tp;
        tp = kc; kc = kn; kn = tp;
        tp = vc; vc = vn; vn = tp;
    }

    #pragma unroll
    for (int st = 0; st < 2; st++)
        #pragma unroll
        for (int r = 0; r < 4; r++) {
            const float linv = 1.0f / __shfl(l_i[st], quad * 4 + r);
            const int row = q0 + w * 32 + st * 16 + quad * 4 + r;
            const size_t base = (size_t)(b * T + row) * 2048 + h * 128;
            #pragma unroll
            for (int c = 0; c < 8; c++)
                Out[base + c * 16 + l16] = f2bf(o[st][c][r] * linv);
        }
}

extern "C" void kernel_launch(void* const* d_in, const int* in_sizes, int n_in,
                              void* d_out, int out_size, void* d_ws, size_t ws_size,
                              hipStream_t stream) {
    const int B = 2, T = 2048, C = 2048;
    const float* x    = (const float*)d_in[0];
    const float* Wqkv = (const float*)d_in[2];   // [C][3C] fp32
    const float* Wout = (const float*)d_in[3];   // [C][C]  fp32
    const int M = B * T;                         // 4096

    char* ws = (char*)d_ws;
    unsigned short* qkv   = (unsigned short*)ws;                       // +0
    unsigned short* xb    = (unsigned short*)(ws + 50331648);          // region A
    unsigned short* WoutT = xb;
    unsigned short* WqkvT = (unsigned short*)(ws + 67108864);          // region B
    unsigned short* VTp   = WqkvT;
    unsigned short* O     = (unsigned short*)(ws + 92274688);

    // One-time: raise dynamic-LDS cap for the 96 KiB ring kernel.
    // Host-side, capture-safe. On failure -> fall back to proven gemm_bt.
    static int bigLds = 0;
    if (bigLds == 0) {
        hipError_t rc = hipFuncSetAttribute(
            reinterpret_cast<const void*>(gemm256r),
            hipFuncAttributeMaxDynamicSharedMemorySize, 98304);
        bigLds = (rc == hipSuccess) ? 1 : -1;
    }

    // 1) prep1: x->bf16 cast (4096 blocks) + Wqkv transpose-cast (3072 blocks)
    prep1<<<dim3(4096 + 3072), 256, 0, stream>>>(x, xb, Wqkv, WqkvT);
    // 2) qkv = xb @ WqkvT^T
    if (bigLds == 1)
        gemm256r<<<dim3(3 * C / 256, M / 256), 512, 98304, stream>>>(xb, WqkvT, qkv, M, 3 * C, C);
    else
        gemm_bt<<<dim3(3 * C / 128, M / 128), 256, 0, stream>>>(xb, WqkvT, qkv, M, 3 * C, C, 0);
    // 3) prep2: V transpose (2048 blocks) + Wout transpose-cast (1024 blocks)
    prep2<<<dim3(2048 + 1024), 256, 0, stream>>>(qkv, VTp, Wout, WoutT);
    // 4) flash attention
    flash_attn<<<dim3(T / 128, B * 16), 256, 0, stream>>>(qkv, VTp, O);
    // 5) out = O @ WoutT^T (fp32 out)
    gemm_bt<<<dim3(C / 128, M / 128), 256, 0, stream>>>(O, WoutT, d_out, M, C, C, 1);
}

// Round 10
// 413.677 us; speedup vs baseline: 1.0168x; 1.0168x over previous
//
#include <hip/hip_runtime.h>
#include <stdint.h>

typedef __bf16 bf16x8 __attribute__((ext_vector_type(8)));
typedef float f32x4 __attribute__((ext_vector_type(4)));
typedef unsigned short u16x8 __attribute__((ext_vector_type(8)));
typedef unsigned int u32x4 __attribute__((ext_vector_type(4)));

__device__ __forceinline__ unsigned short f2bf(float f) {
    unsigned int u = __builtin_bit_cast(unsigned int, f);
    unsigned int r = u + 0x7fffu + ((u >> 16) & 1u);
    return (unsigned short)(r >> 16);
}

// v_cvt_pk_bf16_f32: lo <- bf16(a), hi <- bf16(b)
__device__ __forceinline__ unsigned int cvt_pk_bf16(float a, float b) {
    unsigned int r;
    asm("v_cvt_pk_bf16_f32 %0, %1, %2" : "=v"(r) : "v"(a), "v"(b));
    return r;
}

// async global->LDS, 16B per lane. LDS dest = wave-uniform base + lane*16.
__device__ __forceinline__ void async16(const void* g, void* l) {
    __builtin_amdgcn_global_load_lds(
        (const __attribute__((address_space(1))) void*)g,
        (__attribute__((address_space(3))) void*)l, 16, 0, 0);
}

// ---------------------------------------------------------------------------
// Bodies for the fused prep kernels (block-granular branching).
// ---------------------------------------------------------------------------

// x fp32 -> bf16, 8 elems/thread at flat index i
__device__ __forceinline__ void cast_body(
    const float* __restrict__ src, unsigned short* __restrict__ dst, int i)
{
    const float* f = src + (size_t)i * 8;
    f32x4 a = *reinterpret_cast<const f32x4*>(f);
    f32x4 b = *reinterpret_cast<const f32x4*>(f + 4);
    u16x8 r;
    r[0]=f2bf(a[0]); r[1]=f2bf(a[1]); r[2]=f2bf(a[2]); r[3]=f2bf(a[3]);
    r[4]=f2bf(b[0]); r[5]=f2bf(b[1]); r[6]=f2bf(b[2]); r[7]=f2bf(b[3]);
    *reinterpret_cast<u16x8*>(dst + (size_t)i * 8) = r;
}

// W fp32 [R][Cc] -> bf16 W^T [Cc][R], one 64x64 tile at (bx,by), XOR-swizzled LDS
__device__ __forceinline__ void tcast_body(
    const float* __restrict__ src, unsigned short* __restrict__ dst,
    int R, int Cc, int bx, int by, int tid, unsigned short* St)
{
    const int r0 = by * 64, c0 = bx * 64;
    const int lr  = tid >> 2;          // 0..63
    const int lcb = (tid & 3) * 16;    // 0,16,32,48
    const float* sp = src + (size_t)(r0 + lr) * Cc + c0 + lcb;
    #pragma unroll
    for (int u = 0; u < 4; u++) {
        f32x4 v = *reinterpret_cast<const f32x4*>(sp + 4 * u);
        #pragma unroll
        for (int e = 0; e < 4; e++) {
            int c = lcb + 4 * u + e;
            St[c * 64 + (((lr >> 3) ^ ((c >> 4) & 3)) << 3) + (lr & 7)] = f2bf(v[e]);
        }
    }
    __syncthreads();
    #pragma unroll
    for (int i = 0; i < 2; i++) {
        int ck = tid + 256 * i;
        int c = ck >> 3, ch = ck & 7;
        u16x8 val = *reinterpret_cast<const u16x8*>(&St[c * 64 + ((ch ^ ((c >> 4) & 3)) << 3)]);
        *reinterpret_cast<u16x8*>(dst + (size_t)(c0 + c) * R + r0 + ch * 8) = val;
    }
}

// V-part of qkv -> VT [b][h][d][t'] with per-32 t-permutation matching the
// swapped-QK^T P layout (see flash_attn). One 64x64 tile at (tx, dy, bh).
__device__ __forceinline__ void vtrans_body(
    const unsigned short* __restrict__ qkv, unsigned short* __restrict__ VT,
    int tx, int dy, int bh, int tid, unsigned short* St)
{
    const int T = 2048, CH = 6144;
    const int b = bh >> 4, h = bh & 15;
    const int t0 = tx * 64, d0 = dy * 64;
    const int lr  = tid >> 2;
    const int lcb = (tid & 3) * 16;
    const unsigned short* sp = qkv + (size_t)(b * T + t0 + lr) * CH + 4096 + h * 128 + d0 + lcb;
    u16x8 v0 = *reinterpret_cast<const u16x8*>(sp);
    u16x8 v1 = *reinterpret_cast<const u16x8*>(sp + 8);
    #pragma unroll
    for (int e = 0; e < 8; e++) {
        int c = lcb + e;
        St[c * 64 + (((lr >> 3) ^ ((c >> 4) & 3)) << 3) + (lr & 7)] = v0[e];
        c = lcb + 8 + e;
        St[c * 64 + (((lr >> 3) ^ ((c >> 4) & 3)) << 3) + (lr & 7)] = v1[e];
    }
    __syncthreads();
    #pragma unroll
    for (int i = 0; i < 2; i++) {
        int ck = tid + 256 * i;
        int d = ck >> 3, ch = ck & 7;
        const int Q = ch & 3, B32 = ch >> 2;
        u16x8 val;
        #pragma unroll
        for (int e = 0; e < 4; e++) {
            int ta = 32 * B32 + 4 * Q + e;        // first half of chunk
            int tb = ta + 16;                     // second half
            val[e]     = St[d * 64 + (((ta >> 3) ^ ((d >> 4) & 3)) << 3) + (ta & 7)];
            val[4 + e] = St[d * 64 + (((tb >> 3) ^ ((d >> 4) & 3)) << 3) + (tb & 7)];
        }
        *reinterpret_cast<u16x8*>(VT + (size_t)(bh * 128 + d0 + d) * T + t0 + ch * 8) = val;
    }
}

// ---------------------------------------------------------------------------
// prep1 = cast_bf16(x) U transpose_cast(Wqkv) [U transpose_cast(Wout) when
// launched with 8192 blocks — WoutT de-aliased path].
//   [0,4096)    : cast
//   [4096,7168) : Wqkv transpose
//   [7168,8192) : Wout transpose (only reached when grid = 8192)
// ---------------------------------------------------------------------------
__global__ __launch_bounds__(256) void prep1(
    const float* __restrict__ x, unsigned short* __restrict__ xb,
    const float* __restrict__ Wqkv, unsigned short* __restrict__ WqkvT,
    const float* __restrict__ Wout, unsigned short* __restrict__ WoutT)
{
    __shared__ unsigned short St[64 * 64];
    const int bid = blockIdx.x, tid = threadIdx.x;
    if (bid < 4096) {
        cast_body(x, xb, bid * 256 + tid);
    } else if (bid < 7168) {
        const int b2 = bid - 4096;
        tcast_body(Wqkv, WqkvT, 2048, 6144, b2 % 96, b2 / 96, tid, St);
    } else {
        const int b2 = bid - 7168;
        tcast_body(Wout, WoutT, 2048, 2048, b2 % 32, b2 / 32, tid, St);
    }
}

// ---------------------------------------------------------------------------
// prep2 = vtrans(qkv) [U transpose_cast(Wout) when launched with 3072 blocks
// — fallback path where WoutT aliases xb and must wait for GEMM1].
// ---------------------------------------------------------------------------
__global__ __launch_bounds__(256) void prep2(
    const unsigned short* __restrict__ qkv, unsigned short* __restrict__ VT,
    const float* __restrict__ Wout, unsigned short* __restrict__ WoutT)
{
    __shared__ unsigned short St[64 * 64];
    const int bid = blockIdx.x, tid = threadIdx.x;
    if (bid < 2048) {
        vtrans_body(qkv, VT, bid % 32, (bid >> 5) & 1, bid >> 6, tid, St);
    } else {
        const int b2 = bid - 2048;
        tcast_body(Wout, WoutT, 2048, 2048, b2 % 32, b2 / 32, tid, St);
    }
}

// ---------------------------------------------------------------------------
// 128x128 double-buffered GEMM, single-barrier counted pipeline + T2 swizzle
// (PROVEN 133us/775TF across r4/r5/r8). Structure gambles r3/r6/r7/r9 all
// failed to beat it (static-LDS limit / 256^2-at-2ph / ring-vs-occupancy /
// phase-split-without-stagger) — this is the banked GEMM for both calls.
// ---------------------------------------------------------------------------
__global__ __launch_bounds__(256) void gemm_bt(
    const unsigned short* __restrict__ A,   // [M][K] bf16
    const unsigned short* __restrict__ BT,  // [N][K] bf16
    void* __restrict__ C, int M, int N, int K, int cF32)
{
    __shared__ unsigned short As[2][128 * 32];
    __shared__ unsigned short Bs[2][128 * 32];
    const int tid = threadIdx.x;
    const int w = tid >> 6, lane = tid & 63;
    const int quad = lane >> 4, l16 = lane & 15;
    const int wm = (w >> 1) * 64, wn = (w & 1) * 64;
    const int m0 = blockIdx.y * 128, n0 = blockIdx.x * 128;

    const int srow = w * 16 + (lane >> 2);
    const int scol = ((lane & 3) ^ ((lane >> 3) & 3)) * 8;   // inverse-swizzled source chunk
    const unsigned short* aG = A  + (size_t)(m0 + srow) * K + scol;
    const unsigned short* bG = BT + (size_t)(n0 + srow) * K + scol;
    const int ldsO = (w * 16) * 32;            // wave-uniform LDS offset

    const int kch = (quad ^ ((l16 >> 1) & 3)) * 8;   // swizzled fragment chunk

    f32x4 acc[4][4] = {};
    const int nkt = K >> 5;

    async16(aG, &As[0][ldsO]);
    async16(aG + (size_t)64 * K, &As[0][ldsO + 64 * 32]);
    async16(bG, &Bs[0][ldsO]);
    async16(bG + (size_t)64 * K, &Bs[0][ldsO + 64 * 32]);
    asm volatile("s_waitcnt vmcnt(0)\n\ts_barrier" ::: "memory");

    int ct = 0;
    for (int t = 0; t < nkt; ++t) {
        if (t + 1 < nkt) {
            const int k1 = (t + 1) * 32;
            async16(aG + k1, &As[ct ^ 1][ldsO]);
            async16(aG + (size_t)64 * K + k1, &As[ct ^ 1][ldsO + 64 * 32]);
            async16(bG + k1, &Bs[ct ^ 1][ldsO]);
            async16(bG + (size_t)64 * K + k1, &Bs[ct ^ 1][ldsO + 64 * 32]);
        }

        bf16x8 af[4], bf[4];
        #pragma unroll
        for (int i = 0; i < 4; i++)
            af[i] = *reinterpret_cast<const bf16x8*>(&As[ct][(wm + i * 16 + l16) * 32 + kch]);
        #pragma unroll
        for (int c = 0; c < 4; c++)
            bf[c] = *reinterpret_cast<const bf16x8*>(&Bs[ct][(wn + c * 16 + l16) * 32 + kch]);

        __builtin_amdgcn_s_setprio(1);
        #pragma unroll
        for (int i = 0; i < 4; i++)
            #pragma unroll
            for (int c = 0; c < 4; c++)
                acc[i][c] = __builtin_amdgcn_mfma_f32_16x16x32_bf16(af[i], bf[c], acc[i][c], 0, 0, 0);
        __builtin_amdgcn_s_setprio(0);

        asm volatile("s_waitcnt vmcnt(0) lgkmcnt(0)\n\ts_barrier" ::: "memory");
        ct ^= 1;
    }

    #pragma unroll
    for (int i = 0; i < 4; i++)
        #pragma unroll
        for (int c = 0; c < 4; c++)
            #pragma unroll
            for (int r = 0; r < 4; r++) {
                const int row = m0 + wm + i * 16 + quad * 4 + r;
                const int col = n0 + wn + c * 16 + l16;
                const size_t off = (size_t)row * N + col;
                if (cF32) ((float*)C)[off] = acc[i][c][r];
                else ((unsigned short*)C)[off] = f2bf(acc[i][c][r]);
            }
}

// ---------------------------------------------------------------------------
// Flash attention v2 (causal), swapped-QK^T / lane-local softmax,
// double-buffered K/V staging with counted-vmcnt pipeline (r2-proven), plus
// NEW: wave-level skip of fully-masked tiles — on the diagonal tile
// kv0 = q0+64, waves 0-1 (rows q0..q0+63) have all kv > qrow; their 64 MFMA
// + softmax + LDS reads contribute exactly zero. Skip condition
// kv0 > q0 + w*32 + 31 is w-uniform => wave-uniform branch; staging and
// barriers preserved (all waves still reach the tile-end barrier; vmcnt
// waits only cover the wave's own staging loads).
// ---------------------------------------------------------------------------
__global__ __launch_bounds__(256, 2) void flash_attn(
    const unsigned short* __restrict__ qkv,
    const unsigned short* __restrict__ VT,
    unsigned short* __restrict__ Out)
{
    const int T = 2048, CH = 6144;
    __shared__ unsigned short KsBuf[2][64 * 128];   // [kv][d-chunk swizzled]
    __shared__ unsigned short VtBuf[2][128 * 64];   // [d][kv'-chunk swizzled]

    const int tid = threadIdx.x;
    const int w = tid >> 6, lane = tid & 63;
    const int quad = lane >> 4, l16 = lane & 15;
    const int bh = blockIdx.y, b = bh >> 4, h = bh & 15;
    const int q0 = (gridDim.x - 1 - blockIdx.x) * 128;   // heavy blocks first

    const float sc = 0.08838834764831845f * 1.4426950408889634f;
    const float NINF = -__builtin_inff();

    // Q fragments (B-operand), scale folded in
    bf16x8 qf[2][4];
    #pragma unroll
    for (int st = 0; st < 2; st++) {
        const unsigned short* qrow = qkv + (size_t)(b * T + q0 + w * 32 + st * 16 + l16) * CH + h * 128;
        #pragma unroll
        for (int dc = 0; dc < 4; dc++) {
            u16x8 raw = *reinterpret_cast<const u16x8*>(qrow + dc * 32 + quad * 8);
            u16x8 scl;
            #pragma unroll
            for (int e = 0; e < 8; e++) {
                float f = __builtin_bit_cast(float, (unsigned int)raw[e] << 16);
                scl[e] = f2bf(f * sc);
            }
            qf[st][dc] = __builtin_bit_cast(bf16x8, scl);
        }
    }

    f32x4 o[2][8] = {};
    float m_i[2] = {NINF, NINF};
    float l_i[2] = {0.f, 0.f};
    const int xsw = l16 & 7;

    const int kRow = (lane >> 4);
    const int kCh  = lane & 15;
    const int vRow = (lane >> 3);
    const int vCh  = lane & 7;

    auto stageKV = [&](int kv0, unsigned short* kp, unsigned short* vp) {
        #pragma unroll
        for (int i = 0; i < 4; i++) {
            const int r0 = i * 16 + w * 4;
            const int kv = r0 + kRow;
            const int ch = kCh ^ (kv & 7);
            async16(qkv + (size_t)(b * T + kv0 + kv) * CH + 2048 + h * 128 + ch * 8,
                    kp + r0 * 128);
        }
        #pragma unroll
        for (int i = 0; i < 4; i++) {
            const int r0 = i * 32 + w * 8;
            const int d = r0 + vRow;
            const int ch = vCh ^ (d & 7);
            async16(VT + ((size_t)bh * 128 + d) * T + kv0 + ch * 8,
                    vp + r0 * 64);
        }
    };

    unsigned short* kc = KsBuf[0];
    unsigned short* vc = VtBuf[0];
    unsigned short* kn = KsBuf[1];
    unsigned short* vn = VtBuf[1];

    const int nt = (q0 + 128) / 64;

    stageKV(0, kc, vc);
    asm volatile("s_waitcnt vmcnt(0)\n\ts_barrier" ::: "memory");

    for (int t = 0; t < nt; ++t) {
        const int kv0 = t * 64;
        if (t + 1 < nt) stageKV((t + 1) * 64, kn, vn);

        // wave-uniform: this wave has at least one unmasked row in this tile
        if (kv0 <= q0 + w * 32 + 31) {
            // ---- S^T = K Q^T ----
            f32x4 s[2][4] = {};
            __builtin_amdgcn_s_setprio(1);
            #pragma unroll
            for (int dc = 0; dc < 4; dc++)
                #pragma unroll
                for (int ntt = 0; ntt < 4; ntt++) {
                    bf16x8 kf = *reinterpret_cast<const bf16x8*>(
                        &kc[(ntt * 16 + l16) * 128 + (((dc * 4 + quad) ^ xsw) << 3)]);
                    s[0][ntt] = __builtin_amdgcn_mfma_f32_16x16x32_bf16(kf, qf[0][dc], s[0][ntt], 0, 0, 0);
                    s[1][ntt] = __builtin_amdgcn_mfma_f32_16x16x32_bf16(kf, qf[1][dc], s[1][ntt], 0, 0, 0);
                }
            __builtin_amdgcn_s_setprio(0);

            // ---- softmax, lane-local rows ----
            unsigned int pk[2][4][2];
            #pragma unroll
            for (int st = 0; st < 2; st++) {
                const int qs = q0 + w * 32 + st * 16;
                const int qrow = qs + l16;
                if (kv0 + 63 > qs) {                     // diagonal: causal mask
                    #pragma unroll
                    for (int ntt = 0; ntt < 4; ntt++)
                        #pragma unroll
                        for (int r = 0; r < 4; r++)
                            if (kv0 + ntt * 16 + quad * 4 + r > qrow) s[st][ntt][r] = NINF;
                }
                float mx = fmaxf(fmaxf(fmaxf(s[st][0][0], s[st][0][1]), fmaxf(s[st][0][2], s[st][0][3])),
                                 fmaxf(fmaxf(s[st][1][0], s[st][1][1]), fmaxf(s[st][1][2], s[st][1][3])));
                mx = fmaxf(mx,
                     fmaxf(fmaxf(fmaxf(s[st][2][0], s[st][2][1]), fmaxf(s[st][2][2], s[st][2][3])),
                           fmaxf(fmaxf(s[st][3][0], s[st][3][1]), fmaxf(s[st][3][2], s[st][3][3]))));
                mx = fmaxf(mx, __shfl_xor(mx, 16));
                mx = fmaxf(mx, __shfl_xor(mx, 32));

                const float mold = m_i[st];
                if (!__all(mx <= mold + 8.0f)) {         // rescale (rare)
                    const float mnew = fmaxf(mold, mx);
                    const float alpha = exp2f(mold - mnew);
                    m_i[st] = mnew;
                    l_i[st] *= alpha;
                    #pragma unroll
                    for (int r = 0; r < 4; r++) {
                        const float a = __shfl(alpha, quad * 4 + r);
                        #pragma unroll
                        for (int c = 0; c < 8; c++) o[st][c][r] *= a;
                    }
                }
                const float m = m_i[st];
                float p[4][4];
                #pragma unroll
                for (int ntt = 0; ntt < 4; ntt++)
                    #pragma unroll
                    for (int r = 0; r < 4; r++)
                        p[ntt][r] = exp2f(s[st][ntt][r] - m);
                float ps = ((p[0][0] + p[0][1]) + (p[0][2] + p[0][3]))
                         + ((p[1][0] + p[1][1]) + (p[1][2] + p[1][3]))
                         + ((p[2][0] + p[2][1]) + (p[2][2] + p[2][3]))
                         + ((p[3][0] + p[3][1]) + (p[3][2] + p[3][3]));
                ps += __shfl_xor(ps, 16);
                ps += __shfl_xor(ps, 32);
                l_i[st] += ps;
                #pragma unroll
                for (int ntt = 0; ntt < 4; ntt++) {
                    pk[st][ntt][0] = cvt_pk_bf16(p[ntt][0], p[ntt][1]);
                    pk[st][ntt][1] = cvt_pk_bf16(p[ntt][2], p[ntt][3]);
                }
            }

            // ---- O += P V ----
            __builtin_amdgcn_s_setprio(1);
            #pragma unroll
            for (int kc2 = 0; kc2 < 2; kc2++) {
                u32x4 a0, a1;
                a0[0] = pk[0][2*kc2][0];   a0[1] = pk[0][2*kc2][1];
                a0[2] = pk[0][2*kc2+1][0]; a0[3] = pk[0][2*kc2+1][1];
                a1[0] = pk[1][2*kc2][0];   a1[1] = pk[1][2*kc2][1];
                a1[2] = pk[1][2*kc2+1][0]; a1[3] = pk[1][2*kc2+1][1];
                const bf16x8 pf0 = __builtin_bit_cast(bf16x8, a0);
                const bf16x8 pf1 = __builtin_bit_cast(bf16x8, a1);
                #pragma unroll
                for (int c = 0; c < 8; c++) {
                    bf16x8 vf = *reinterpret_cast<const bf16x8*>(
                        &vc[(c * 16 + l16) * 64 + (((kc2 * 4 + quad) ^ xsw) << 3)]);
                    o[0][c] = __builtin_amdgcn_mfma_f32_16x16x32_bf16(pf0, vf, o[0][c], 0, 0, 0);
                    o[1][c] = __builtin_amdgcn_mfma_f32_16x16x32_bf16(pf1, vf, o[1][c], 0, 0, 0);
                }
            }
            __builtin_amdgcn_s_setprio(0);
        }

        asm volatile("s_waitcnt vmcnt(0) lgkmcnt(0)\n\ts_barrier" ::: "memory");

        unsigned short* tp;
        tp = kc; kc = kn; kn = tp;
        tp = vc; vc = vn; vn = tp;
    }

    #pragma unroll
    for (int st = 0; st < 2; st++)
        #pragma unroll
        for (int r = 0; r < 4; r++) {
            const float linv = 1.0f / __shfl(l_i[st], quad * 4 + r);
            const int row = q0 + w * 32 + st * 16 + quad * 4 + r;
            const size_t base = (size_t)(b * T + row) * 2048 + h * 128;
            #pragma unroll
            for (int c = 0; c < 8; c++)
                Out[base + c * 16 + l16] = f2bf(o[st][c][r] * linv);
        }
}

extern "C" void kernel_launch(void* const* d_in, const int* in_sizes, int n_in,
                              void* d_out, int out_size, void* d_ws, size_t ws_size,
                              hipStream_t stream) {
    const int B = 2, T = 2048, C = 2048;
    const float* x    = (const float*)d_in[0];
    const float* Wqkv = (const float*)d_in[2];   // [C][3C] fp32
    const float* Wout = (const float*)d_in[3];   // [C][C]  fp32
    const int M = B * T;                         // 4096

    char* ws = (char*)d_ws;
    unsigned short* qkv   = (unsigned short*)ws;                       // +0      (50.3 MB)
    unsigned short* xb    = (unsigned short*)(ws + 50331648);          // region A (16.8 MB)
    unsigned short* WqkvT = (unsigned short*)(ws + 67108864);          // region B (25.2 MB)
    unsigned short* VTp   = WqkvT;
    unsigned short* O     = (unsigned short*)(ws + 92274688);          // 16.8 MB -> ends 109051904

    // WoutT placement: prefer a dedicated region past O (lets the Wout
    // transpose run in prep1, concurrent with the x/Wqkv prep, instead of
    // waiting for GEMM1 to free xb). Fall back to the proven aliased layout.
    const bool dealias = (ws_size >= (size_t)117440512);
    unsigned short* WoutT = dealias ? (unsigned short*)(ws + 109051904) : xb;

    // 1) prep1: x cast (4096) + Wqkv transpose (3072) [+ Wout transpose (1024)]
    prep1<<<dim3(dealias ? 8192 : 7168), 256, 0, stream>>>(x, xb, Wqkv, WqkvT, Wout, WoutT);
    // 2) qkv = xb @ WqkvT^T
    gemm_bt<<<dim3(3 * C / 128, M / 128), 256, 0, stream>>>(xb, WqkvT, qkv, M, 3 * C, C, 0);
    // 3) prep2: vtrans (2048) [+ Wout transpose (1024) on the fallback path]
    prep2<<<dim3(dealias ? 2048 : 3072), 256, 0, stream>>>(qkv, VTp, Wout, WoutT);
    // 4) flash attention
    flash_attn<<<dim3(T / 128, B * 16), 256, 0, stream>>>(qkv, VTp, O);
    // 5) out = O @ WoutT^T (fp32 out)
    gemm_bt<<<dim3(C / 128, M / 128), 256, 0, stream>>>(O, WoutT, d_out, M, C, C, 1);
}

// Round 11
// 406.799 us; speedup vs baseline: 1.0340x; 1.0169x over previous
//
#include <hip/hip_runtime.h>
#include <stdint.h>

typedef __bf16 bf16x8 __attribute__((ext_vector_type(8)));
typedef float f32x4 __attribute__((ext_vector_type(4)));
typedef unsigned short u16x8 __attribute__((ext_vector_type(8)));
typedef unsigned short u16x4 __attribute__((ext_vector_type(4)));
typedef unsigned int u32x4 __attribute__((ext_vector_type(4)));

__device__ __forceinline__ unsigned short f2bf(float f) {
    unsigned int u = __builtin_bit_cast(unsigned int, f);
    unsigned int r = u + 0x7fffu + ((u >> 16) & 1u);
    return (unsigned short)(r >> 16);
}

// v_cvt_pk_bf16_f32: lo <- bf16(a), hi <- bf16(b)
__device__ __forceinline__ unsigned int cvt_pk_bf16(float a, float b) {
    unsigned int r;
    asm("v_cvt_pk_bf16_f32 %0, %1, %2" : "=v"(r) : "v"(a), "v"(b));
    return r;
}

// async global->LDS, 16B per lane. LDS dest = wave-uniform base + lane*16.
__device__ __forceinline__ void async16(const void* g, void* l) {
    __builtin_amdgcn_global_load_lds(
        (const __attribute__((address_space(1))) void*)g,
        (__attribute__((address_space(3))) void*)l, 16, 0, 0);
}

// ---------------------------------------------------------------------------
// Prep bodies (block-granular branching).
// ---------------------------------------------------------------------------

// x fp32 -> bf16, 8 elems/thread at flat index i
__device__ __forceinline__ void cast_body(
    const float* __restrict__ src, unsigned short* __restrict__ dst, int i)
{
    const float* f = src + (size_t)i * 8;
    f32x4 a = *reinterpret_cast<const f32x4*>(f);
    f32x4 b = *reinterpret_cast<const f32x4*>(f + 4);
    u16x8 r;
    r[0]=f2bf(a[0]); r[1]=f2bf(a[1]); r[2]=f2bf(a[2]); r[3]=f2bf(a[3]);
    r[4]=f2bf(b[0]); r[5]=f2bf(b[1]); r[6]=f2bf(b[2]); r[7]=f2bf(b[3]);
    *reinterpret_cast<u16x8*>(dst + (size_t)i * 8) = r;
}

// W fp32 [R][Cc] -> bf16 W^T [Cc][R], one 64x64 tile at (bx,by), XOR-swizzled LDS
__device__ __forceinline__ void tcast_body(
    const float* __restrict__ src, unsigned short* __restrict__ dst,
    int R, int Cc, int bx, int by, int tid, unsigned short* St)
{
    const int r0 = by * 64, c0 = bx * 64;
    const int lr  = tid >> 2;          // 0..63
    const int lcb = (tid & 3) * 16;    // 0,16,32,48
    const float* sp = src + (size_t)(r0 + lr) * Cc + c0 + lcb;
    #pragma unroll
    for (int u = 0; u < 4; u++) {
        f32x4 v = *reinterpret_cast<const f32x4*>(sp + 4 * u);
        #pragma unroll
        for (int e = 0; e < 4; e++) {
            int c = lcb + 4 * u + e;
            St[c * 64 + (((lr >> 3) ^ ((c >> 4) & 3)) << 3) + (lr & 7)] = f2bf(v[e]);
        }
    }
    __syncthreads();
    #pragma unroll
    for (int i = 0; i < 2; i++) {
        int ck = tid + 256 * i;
        int c = ck >> 3, ch = ck & 7;
        u16x8 val = *reinterpret_cast<const u16x8*>(&St[c * 64 + ((ch ^ ((c >> 4) & 3)) << 3)]);
        *reinterpret_cast<u16x8*>(dst + (size_t)(c0 + c) * R + r0 + ch * 8) = val;
    }
}

// ---------------------------------------------------------------------------
// prep1 = cast_bf16(x) U transpose_cast(Wqkv).
//   [0,4096)    : cast
//   [4096,7168) : Wqkv transpose
// ---------------------------------------------------------------------------
__global__ __launch_bounds__(256) void prep1(
    const float* __restrict__ x, unsigned short* __restrict__ xb,
    const float* __restrict__ Wqkv, unsigned short* __restrict__ WqkvT)
{
    __shared__ unsigned short St[64 * 64];
    const int bid = blockIdx.x, tid = threadIdx.x;
    if (bid < 4096) {
        cast_body(x, xb, bid * 256 + tid);
    } else {
        const int b2 = bid - 4096;
        tcast_body(Wqkv, WqkvT, 2048, 6144, b2 % 96, b2 / 96, tid, St);
    }
}

// ---------------------------------------------------------------------------
// prep2 = transpose_cast(Wout) only (1024 blocks). vtrans is GONE — GEMM1
// writes VT directly from registers. WoutT aliases xb (free after GEMM1).
// ---------------------------------------------------------------------------
__global__ __launch_bounds__(256) void prep2(
    const float* __restrict__ Wout, unsigned short* __restrict__ WoutT)
{
    __shared__ unsigned short St[64 * 64];
    const int bid = blockIdx.x, tid = threadIdx.x;
    tcast_body(Wout, WoutT, 2048, 2048, bid % 32, bid / 32, tid, St);
}

// ---------------------------------------------------------------------------
// 128x128 double-buffered GEMM, single-barrier counted pipeline + T2 swizzle
// (PROVEN 133us/775TF). NEW: epilogue writes C with stride ldc; when VTd is
// non-null and this block's columns are V (n0 >= 4096), the output is
// emitted DIRECTLY in the VT [bh][d][t'] layout (t' = per-64 k-permutation
// matching flash's swapped-QK^T P layout), skipping the qkv V write and the
// old vtrans pass entirely.
//   Derivation (verified against vtrans_body): thread (quad,l16) holds
//   V[t=m0+wm+i*16+quad*4+r][d=wn+c*16+l16]; perm p(t within 64) =
//   (t>>5&1)*32+((t>>2)&3)*8+((t>>4)&1)*4+(t&3) collapses (base bits 4,5 = i)
//   to p = (i>>1)*32 + quad*8 + (i&1)*4 + r -> r=0..3 consecutive -> one
//   aligned 8B ushort4 store per (i,c). Values f2bf(acc) = bit-identical to
//   the old qkv-write + vtrans-copy path.
// ---------------------------------------------------------------------------
__global__ __launch_bounds__(256) void gemm_bt(
    const unsigned short* __restrict__ A,   // [M][K] bf16
    const unsigned short* __restrict__ BT,  // [N][K] bf16
    void* __restrict__ C, int M, int N, int K, int cF32, int ldc,
    unsigned short* __restrict__ VTd)       // null => plain C write
{
    __shared__ unsigned short As[2][128 * 32];
    __shared__ unsigned short Bs[2][128 * 32];
    const int tid = threadIdx.x;
    const int w = tid >> 6, lane = tid & 63;
    const int quad = lane >> 4, l16 = lane & 15;
    const int wm = (w >> 1) * 64, wn = (w & 1) * 64;
    const int m0 = blockIdx.y * 128, n0 = blockIdx.x * 128;

    const int srow = w * 16 + (lane >> 2);
    const int scol = ((lane & 3) ^ ((lane >> 3) & 3)) * 8;   // inverse-swizzled source chunk
    const unsigned short* aG = A  + (size_t)(m0 + srow) * K + scol;
    const unsigned short* bG = BT + (size_t)(n0 + srow) * K + scol;
    const int ldsO = (w * 16) * 32;            // wave-uniform LDS offset

    const int kch = (quad ^ ((l16 >> 1) & 3)) * 8;   // swizzled fragment chunk

    f32x4 acc[4][4] = {};
    const int nkt = K >> 5;

    async16(aG, &As[0][ldsO]);
    async16(aG + (size_t)64 * K, &As[0][ldsO + 64 * 32]);
    async16(bG, &Bs[0][ldsO]);
    async16(bG + (size_t)64 * K, &Bs[0][ldsO + 64 * 32]);
    asm volatile("s_waitcnt vmcnt(0)\n\ts_barrier" ::: "memory");

    int ct = 0;
    for (int t = 0; t < nkt; ++t) {
        if (t + 1 < nkt) {
            const int k1 = (t + 1) * 32;
            async16(aG + k1, &As[ct ^ 1][ldsO]);
            async16(aG + (size_t)64 * K + k1, &As[ct ^ 1][ldsO + 64 * 32]);
            async16(bG + k1, &Bs[ct ^ 1][ldsO]);
            async16(bG + (size_t)64 * K + k1, &Bs[ct ^ 1][ldsO + 64 * 32]);
        }

        bf16x8 af[4], bf[4];
        #pragma unroll
        for (int i = 0; i < 4; i++)
            af[i] = *reinterpret_cast<const bf16x8*>(&As[ct][(wm + i * 16 + l16) * 32 + kch]);
        #pragma unroll
        for (int c = 0; c < 4; c++)
            bf[c] = *reinterpret_cast<const bf16x8*>(&Bs[ct][(wn + c * 16 + l16) * 32 + kch]);

        __builtin_amdgcn_s_setprio(1);
        #pragma unroll
        for (int i = 0; i < 4; i++)
            #pragma unroll
            for (int c = 0; c < 4; c++)
                acc[i][c] = __builtin_amdgcn_mfma_f32_16x16x32_bf16(af[i], bf[c], acc[i][c], 0, 0, 0);
        __builtin_amdgcn_s_setprio(0);

        asm volatile("s_waitcnt vmcnt(0) lgkmcnt(0)\n\ts_barrier" ::: "memory");
        ct ^= 1;
    }

    if (VTd != nullptr && n0 >= 4096) {
        // direct-VT epilogue (V columns of GEMM1)
        const int h = (n0 - 4096) >> 7;
        #pragma unroll
        for (int i = 0; i < 4; i++) {
            const int row = m0 + wm + i * 16 + quad * 4;   // +r packed in store
            const int b = row >> 11;
            const int t64 = (row & 2047) & ~63;
            const int p = (i >> 1) * 32 + quad * 8 + (i & 1) * 4;
            #pragma unroll
            for (int c = 0; c < 4; c++) {
                const int d = wn + c * 16 + l16;
                u16x4 val;
                val[0] = f2bf(acc[i][c][0]);
                val[1] = f2bf(acc[i][c][1]);
                val[2] = f2bf(acc[i][c][2]);
                val[3] = f2bf(acc[i][c][3]);
                *reinterpret_cast<u16x4*>(
                    VTd + ((size_t)((b * 16 + h) * 128 + d)) * 2048 + t64 + p) = val;
            }
        }
    } else {
        #pragma unroll
        for (int i = 0; i < 4; i++)
            #pragma unroll
            for (int c = 0; c < 4; c++)
                #pragma unroll
                for (int r = 0; r < 4; r++) {
                    const int row = m0 + wm + i * 16 + quad * 4 + r;
                    const int col = n0 + wn + c * 16 + l16;
                    const size_t off = (size_t)row * ldc + col;
                    if (cF32) ((float*)C)[off] = acc[i][c][r];
                    else ((unsigned short*)C)[off] = f2bf(acc[i][c][r]);
                }
    }
}

// ---------------------------------------------------------------------------
// Flash attention v2 (causal), swapped-QK^T / lane-local softmax,
// double-buffered K/V staging with counted-vmcnt pipeline + wave-level
// masked-tile skip (r10-proven). Q/K now read from the 4096-wide QK-only
// buffer (CH=4096); V staged from VT (unchanged).
// ---------------------------------------------------------------------------
__global__ __launch_bounds__(256, 2) void flash_attn(
    const unsigned short* __restrict__ qkv,   // [B*T][4096] Q|K bf16
    const unsigned short* __restrict__ VT,
    unsigned short* __restrict__ Out)
{
    const int T = 2048, CH = 4096;
    __shared__ unsigned short KsBuf[2][64 * 128];   // [kv][d-chunk swizzled]
    __shared__ unsigned short VtBuf[2][128 * 64];   // [d][kv'-chunk swizzled]

    const int tid = threadIdx.x;
    const int w = tid >> 6, lane = tid & 63;
    const int quad = lane >> 4, l16 = lane & 15;
    const int bh = blockIdx.y, b = bh >> 4, h = bh & 15;
    const int q0 = (gridDim.x - 1 - blockIdx.x) * 128;   // heavy blocks first

    const float sc = 0.08838834764831845f * 1.4426950408889634f;
    const float NINF = -__builtin_inff();

    // Q fragments (B-operand), scale folded in
    bf16x8 qf[2][4];
    #pragma unroll
    for (int st = 0; st < 2; st++) {
        const unsigned short* qrow = qkv + (size_t)(b * T + q0 + w * 32 + st * 16 + l16) * CH + h * 128;
        #pragma unroll
        for (int dc = 0; dc < 4; dc++) {
            u16x8 raw = *reinterpret_cast<const u16x8*>(qrow + dc * 32 + quad * 8);
            u16x8 scl;
            #pragma unroll
            for (int e = 0; e < 8; e++) {
                float f = __builtin_bit_cast(float, (unsigned int)raw[e] << 16);
                scl[e] = f2bf(f * sc);
            }
            qf[st][dc] = __builtin_bit_cast(bf16x8, scl);
        }
    }

    f32x4 o[2][8] = {};
    float m_i[2] = {NINF, NINF};
    float l_i[2] = {0.f, 0.f};
    const int xsw = l16 & 7;

    const int kRow = (lane >> 4);
    const int kCh  = lane & 15;
    const int vRow = (lane >> 3);
    const int vCh  = lane & 7;

    auto stageKV = [&](int kv0, unsigned short* kp, unsigned short* vp) {
        #pragma unroll
        for (int i = 0; i < 4; i++) {
            const int r0 = i * 16 + w * 4;
            const int kv = r0 + kRow;
            const int ch = kCh ^ (kv & 7);
            async16(qkv + (size_t)(b * T + kv0 + kv) * CH + 2048 + h * 128 + ch * 8,
                    kp + r0 * 128);
        }
        #pragma unroll
        for (int i = 0; i < 4; i++) {
            const int r0 = i * 32 + w * 8;
            const int d = r0 + vRow;
            const int ch = vCh ^ (d & 7);
            async16(VT + ((size_t)bh * 128 + d) * T + kv0 + ch * 8,
                    vp + r0 * 64);
        }
    };

    unsigned short* kc = KsBuf[0];
    unsigned short* vc = VtBuf[0];
    unsigned short* kn = KsBuf[1];
    unsigned short* vn = VtBuf[1];

    const int nt = (q0 + 128) / 64;

    stageKV(0, kc, vc);
    asm volatile("s_waitcnt vmcnt(0)\n\ts_barrier" ::: "memory");

    for (int t = 0; t < nt; ++t) {
        const int kv0 = t * 64;
        if (t + 1 < nt) stageKV((t + 1) * 64, kn, vn);

        // wave-uniform: this wave has at least one unmasked row in this tile
        if (kv0 <= q0 + w * 32 + 31) {
            // ---- S^T = K Q^T ----
            f32x4 s[2][4] = {};
            __builtin_amdgcn_s_setprio(1);
            #pragma unroll
            for (int dc = 0; dc < 4; dc++)
                #pragma unroll
                for (int ntt = 0; ntt < 4; ntt++) {
                    bf16x8 kf = *reinterpret_cast<const bf16x8*>(
                        &kc[(ntt * 16 + l16) * 128 + (((dc * 4 + quad) ^ xsw) << 3)]);
                    s[0][ntt] = __builtin_amdgcn_mfma_f32_16x16x32_bf16(kf, qf[0][dc], s[0][ntt], 0, 0, 0);
                    s[1][ntt] = __builtin_amdgcn_mfma_f32_16x16x32_bf16(kf, qf[1][dc], s[1][ntt], 0, 0, 0);
                }
            __builtin_amdgcn_s_setprio(0);

            // ---- softmax, lane-local rows ----
            unsigned int pk[2][4][2];
            #pragma unroll
            for (int st = 0; st < 2; st++) {
                const int qs = q0 + w * 32 + st * 16;
                const int qrow = qs + l16;
                if (kv0 + 63 > qs) {                     // diagonal: causal mask
                    #pragma unroll
                    for (int ntt = 0; ntt < 4; ntt++)
                        #pragma unroll
                        for (int r = 0; r < 4; r++)
                            if (kv0 + ntt * 16 + quad * 4 + r > qrow) s[st][ntt][r] = NINF;
                }
                float mx = fmaxf(fmaxf(fmaxf(s[st][0][0], s[st][0][1]), fmaxf(s[st][0][2], s[st][0][3])),
                                 fmaxf(fmaxf(s[st][1][0], s[st][1][1]), fmaxf(s[st][1][2], s[st][1][3])));
                mx = fmaxf(mx,
                     fmaxf(fmaxf(fmaxf(s[st][2][0], s[st][2][1]), fmaxf(s[st][2][2], s[st][2][3])),
                           fmaxf(fmaxf(s[st][3][0], s[st][3][1]), fmaxf(s[st][3][2], s[st][3][3]))));
                mx = fmaxf(mx, __shfl_xor(mx, 16));
                mx = fmaxf(mx, __shfl_xor(mx, 32));

                const float mold = m_i[st];
                if (!__all(mx <= mold + 8.0f)) {         // rescale (rare)
                    const float mnew = fmaxf(mold, mx);
                    const float alpha = exp2f(mold - mnew);
                    m_i[st] = mnew;
                    l_i[st] *= alpha;
                    #pragma unroll
                    for (int r = 0; r < 4; r++) {
                        const float a = __shfl(alpha, quad * 4 + r);
                        #pragma unroll
                        for (int c = 0; c < 8; c++) o[st][c][r] *= a;
                    }
                }
                const float m = m_i[st];
                float p[4][4];
                #pragma unroll
                for (int ntt = 0; ntt < 4; ntt++)
                    #pragma unroll
                    for (int r = 0; r < 4; r++)
                        p[ntt][r] = exp2f(s[st][ntt][r] - m);
                float ps = ((p[0][0] + p[0][1]) + (p[0][2] + p[0][3]))
                         + ((p[1][0] + p[1][1]) + (p[1][2] + p[1][3]))
                         + ((p[2][0] + p[2][1]) + (p[2][2] + p[2][3]))
                         + ((p[3][0] + p[3][1]) + (p[3][2] + p[3][3]));
                ps += __shfl_xor(ps, 16);
                ps += __shfl_xor(ps, 32);
                l_i[st] += ps;
                #pragma unroll
                for (int ntt = 0; ntt < 4; ntt++) {
                    pk[st][ntt][0] = cvt_pk_bf16(p[ntt][0], p[ntt][1]);
                    pk[st][ntt][1] = cvt_pk_bf16(p[ntt][2], p[ntt][3]);
                }
            }

            // ---- O += P V ----
            __builtin_amdgcn_s_setprio(1);
            #pragma unroll
            for (int kc2 = 0; kc2 < 2; kc2++) {
                u32x4 a0, a1;
                a0[0] = pk[0][2*kc2][0];   a0[1] = pk[0][2*kc2][1];
                a0[2] = pk[0][2*kc2+1][0]; a0[3] = pk[0][2*kc2+1][1];
                a1[0] = pk[1][2*kc2][0];   a1[1] = pk[1][2*kc2][1];
                a1[2] = pk[1][2*kc2+1][0]; a1[3] = pk[1][2*kc2+1][1];
                const bf16x8 pf0 = __builtin_bit_cast(bf16x8, a0);
                const bf16x8 pf1 = __builtin_bit_cast(bf16x8, a1);
                #pragma unroll
                for (int c = 0; c < 8; c++) {
                    bf16x8 vf = *reinterpret_cast<const bf16x8*>(
                        &vc[(c * 16 + l16) * 64 + (((kc2 * 4 + quad) ^ xsw) << 3)]);
                    o[0][c] = __builtin_amdgcn_mfma_f32_16x16x32_bf16(pf0, vf, o[0][c], 0, 0, 0);
                    o[1][c] = __builtin_amdgcn_mfma_f32_16x16x32_bf16(pf1, vf, o[1][c], 0, 0, 0);
                }
            }
            __builtin_amdgcn_s_setprio(0);
        }

        asm volatile("s_waitcnt vmcnt(0) lgkmcnt(0)\n\ts_barrier" ::: "memory");

        unsigned short* tp;
        tp = kc; kc = kn; kn = tp;
        tp = vc; vc = vn; vn = tp;
    }

    #pragma unroll
    for (int st = 0; st < 2; st++)
        #pragma unroll
        for (int r = 0; r < 4; r++) {
            const float linv = 1.0f / __shfl(l_i[st], quad * 4 + r);
            const int row = q0 + w * 32 + st * 16 + quad * 4 + r;
            const size_t base = (size_t)(b * T + row) * 2048 + h * 128;
            #pragma unroll
            for (int c = 0; c < 8; c++)
                Out[base + c * 16 + l16] = f2bf(o[st][c][r] * linv);
        }
}

extern "C" void kernel_launch(void* const* d_in, const int* in_sizes, int n_in,
                              void* d_out, int out_size, void* d_ws, size_t ws_size,
                              hipStream_t stream) {
    const int B = 2, T = 2048, C = 2048;
    const float* x    = (const float*)d_in[0];
    const float* Wqkv = (const float*)d_in[2];   // [C][3C] fp32
    const float* Wout = (const float*)d_in[3];   // [C][C]  fp32
    const int M = B * T;                         // 4096

    // Workspace layout (fits in the known-available 104 MiB):
    //   qkvQK [4096][4096] bf16 : 33.5 MB @ 0          (Q|K only — V goes to VT)
    //   xb    [4096][2048] bf16 : 16.8 MB @ 33554432   (WoutT aliases after GEMM1)
    //   WqkvT [6144][2048] bf16 : 25.2 MB @ 50331648
    //   VT    [32][128][2048]   : 16.8 MB @ 75497472   (disjoint from WqkvT!)
    //   O     [4096][2048] bf16 : 16.8 MB @ 92274688
    char* ws = (char*)d_ws;
    unsigned short* qkvQK = (unsigned short*)ws;
    unsigned short* xb    = (unsigned short*)(ws + 33554432);
    unsigned short* WoutT = xb;
    unsigned short* WqkvT = (unsigned short*)(ws + 50331648);
    unsigned short* VTp   = (unsigned short*)(ws + 75497472);
    unsigned short* O     = (unsigned short*)(ws + 92274688);

    // 1) prep1: x cast (4096) + Wqkv transpose (3072)
    prep1<<<dim3(4096 + 3072), 256, 0, stream>>>(x, xb, Wqkv, WqkvT);
    // 2) qkv = xb @ WqkvT^T — Q/K to qkvQK (ldc=4096), V DIRECT to VT
    gemm_bt<<<dim3(3 * C / 128, M / 128), 256, 0, stream>>>(
        xb, WqkvT, qkvQK, M, 3 * C, C, 0, 4096, VTp);
    // 3) prep2: Wout transpose only (WoutT aliases xb, free after GEMM1)
    prep2<<<dim3(1024), 256, 0, stream>>>(Wout, WoutT);
    // 4) flash attention (Q/K stride 4096; V from VT)
    flash_attn<<<dim3(T / 128, B * 16), 256, 0, stream>>>(qkvQK, VTp, O);
    // 5) out = O @ WoutT^T (fp32 out, plain epilogue)
    gemm_bt<<<dim3(C / 128, M / 128), 256, 0, stream>>>(
        O, WoutT, d_out, M, C, C, 1, C, nullptr);
}